// Round 15
// baseline (186.250 us; speedup 1.0000x reference)
//
#include <hip/hip_runtime.h>
#include <hip/hip_fp16.h>

using f16x8 = __attribute__((ext_vector_type(8))) _Float16;
using f32x4 = __attribute__((ext_vector_type(4))) float;

// ---------------- fused: layer-1 MFMA GEMM  ||  degree count+pos ----------------

__global__ __launch_bounds__(256) void k_gemm_count(
    const float* __restrict__ x, const float* __restrict__ W,
    __half* __restrict__ h1, int n,
    const int* __restrict__ dst, int* __restrict__ deg,
    int* __restrict__ pos, int e, int gemmBlocks) {
    __shared__ _Float16 Wf[8 * 4 * 64 * 8];   // 32 KB (gemm path only)
    int t = threadIdx.x;

    if ((int)blockIdx.x >= gemmBlocks) {
        // ---- count path ----
        int cb = blockIdx.x - gemmBlocks;
        int i = cb * 256 + t;
        int stride = (gridDim.x - gemmBlocks) * 256;
        for (; i < e; i += stride) pos[i] = atomicAdd(&deg[dst[i]], 1);
        return;
    }

    // ---- gemm path ----
    const float4* Wg4 = (const float4*)W;
#pragma unroll
    for (int ii = 0; ii < 16; ++ii) {
        int idx4 = t + 256 * ii;            // float4 index 0..4095
        int k  = idx4 >> 5;                 // 0..127
        int n0 = (idx4 & 31) * 4;           // 0..124
        float4 w = Wg4[idx4];
        int nt = n0 >> 4;
        int kc = k >> 5;
        int ln = ((k >> 3) & 3) * 16 + (n0 & 15);
        int i  = k & 7;
        int base = (((nt << 2) + kc) * 64 + ln) * 8 + i;
        Wf[base]      = (_Float16)w.x;
        Wf[base + 8]  = (_Float16)w.y;
        Wf[base + 16] = (_Float16)w.z;
        Wf[base + 24] = (_Float16)w.w;
    }
    __syncthreads();

    int lane = t & 63;
    int w_id = t >> 6;
    int row0 = blockIdx.x * 64 + w_id * 16;
    int arow = row0 + (lane & 15);
    if (arow >= n) arow = n - 1;
    int kb = (lane >> 4) * 8;

    f32x4 acc[8];
#pragma unroll
    for (int nt = 0; nt < 8; ++nt) acc[nt] = (f32x4){0.f, 0.f, 0.f, 0.f};

    const float* xr = x + (size_t)arow * 128;
#pragma unroll
    for (int kc = 0; kc < 4; ++kc) {
        float4 xa = *(const float4*)(xr + kc * 32 + kb);
        float4 xb = *(const float4*)(xr + kc * 32 + kb + 4);
        f16x8 a;
        a[0] = (_Float16)xa.x; a[1] = (_Float16)xa.y;
        a[2] = (_Float16)xa.z; a[3] = (_Float16)xa.w;
        a[4] = (_Float16)xb.x; a[5] = (_Float16)xb.y;
        a[6] = (_Float16)xb.z; a[7] = (_Float16)xb.w;
#pragma unroll
        for (int nt = 0; nt < 8; ++nt) {
            f16x8 b = *(const f16x8*)&Wf[(((nt << 2) + kc) * 64 + lane) * 8];
            acc[nt] = __builtin_amdgcn_mfma_f32_16x16x32_f16(a, b, acc[nt], 0, 0, 0);
        }
    }

    int drow = row0 + (lane >> 4) * 4;
#pragma unroll
    for (int r = 0; r < 4; ++r) {
        int grow = drow + r;
        if (grow < n) {
#pragma unroll
            for (int nt = 0; nt < 8; ++nt)
                h1[(size_t)grow * 128 + nt * 16 + (lane & 15)] =
                    __float2half(acc[nt][r]);
        }
    }
}

// pass 1: per-block (512 elems) sums + dinv = rsqrt(deg+1)
__global__ __launch_bounds__(512) void k_scan1(const int* __restrict__ deg,
                                               float* __restrict__ dinv,
                                               int* __restrict__ bsum, int n) {
    int t = threadIdx.x;
    int i = blockIdx.x * 512 + t;
    int d = (i < n) ? deg[i] : 0;
    if (i < n) dinv[i] = rsqrtf((float)(d + 1));   // +1 self-loop
    int v = d;
#pragma unroll
    for (int off = 32; off > 0; off >>= 1) v += __shfl_xor(v, off, 64);
    __shared__ int wsum[8];
    if ((t & 63) == 0) wsum[t >> 6] = v;
    __syncthreads();
    if (t == 0) {
        int s = 0;
#pragma unroll
        for (int j = 0; j < 8; ++j) s += wsum[j];
        bsum[blockIdx.x] = s;
    }
}

// pass 2 (merged): block offset from bsum in-block, then local scan -> rowptr
__global__ __launch_bounds__(512) void k_scan3(const int* __restrict__ deg,
                                               const int* __restrict__ bsum,
                                               int* __restrict__ rowptr, int n) {
    __shared__ int sm[512];
    __shared__ int sboff;
    int t = threadIdx.x;
    int v = (t < blockIdx.x) ? bsum[t] : 0;
#pragma unroll
    for (int off = 32; off > 0; off >>= 1) v += __shfl_xor(v, off, 64);
    if ((t & 63) == 0) sm[t >> 6] = v;
    __syncthreads();
    if (t == 0) {
        int s = 0;
#pragma unroll
        for (int j = 0; j < 8; ++j) s += sm[j];
        sboff = s;
    }
    __syncthreads();
    int boff = sboff;
    __syncthreads();                     // sm reuse barrier
    int i = blockIdx.x * 512 + t;
    int d = (i < n) ? deg[i] : 0;
    sm[t] = d;
    __syncthreads();
    for (int dd = 1; dd < 512; dd <<= 1) {
        int vv = (t >= dd) ? sm[t - dd] : 0;
        __syncthreads();
        sm[t] += vv;
        __syncthreads();
    }
    int excl = sm[t] - d;
    if (i < n) {
        rowptr[i] = boff + excl;
        if (i == n - 1) rowptr[n] = boff + excl + d;
    }
}

// atomic-free fill of packed edge records {src, norm=dinv[src]*dinv[dst]}
__global__ void k_fill(const int* __restrict__ src, const int* __restrict__ dst,
                       const int* __restrict__ pos, const int* __restrict__ rowptr,
                       const float* __restrict__ dinv,
                       int2* __restrict__ enorm, int e) {
    int i = blockIdx.x * blockDim.x + threadIdx.x;
    int stride = gridDim.x * blockDim.x;
    for (; i < e; i += stride) {
        int ss = src[i];
        int dd = dst[i];
        float nn = dinv[ss] * dinv[dd];
        enorm[rowptr[dd] + pos[i]] = make_int2(ss, __float_as_int(nn));
    }
}

// ---------------- fused layer-1 agg + bias + relu + W2 dot ----------------
// 2 nodes per wave: 32-lane halves, lane covers 4 cols (8B uint2 gathers);
// edge loop unrolled x8 for MLP.

__global__ __launch_bounds__(256) void k_agg_s(
    const int* __restrict__ rowptr, const int2* __restrict__ enorm,
    const float* __restrict__ dinv, const __half* __restrict__ h1,
    const float* __restrict__ b1, const float* __restrict__ W2,
    float* __restrict__ s, int n) {
    int lane = threadIdx.x & 63;
    int half = lane >> 5;
    int sl = lane & 31;
    int wv = blockIdx.x * (blockDim.x >> 6) + (threadIdx.x >> 6);
    int nw = gridDim.x * (blockDim.x >> 6);
    float4 bb = ((const float4*)b1)[sl];   // cols 4sl..4sl+3
    float4 ww = ((const float4*)W2)[sl];
    for (int base = wv * 2; base < n; base += nw * 2) {
        int i = base + half;
        int iq = (i < n) ? i : (n - 1);
        float di = dinv[iq];
        uint2 rv = ((const uint2*)(h1 + (size_t)iq * 128))[sl];
        float2 f0 = __half22float2(*(__half2*)&rv.x);
        float2 f1 = __half22float2(*(__half2*)&rv.y);
        float self = di * di;
        float4 acc = make_float4(f0.x * self, f0.y * self, f1.x * self, f1.y * self);
        int j = rowptr[iq], end = rowptr[iq + 1];
        for (; j + 8 <= end; j += 8) {
            int2 er[8];
#pragma unroll
            for (int q = 0; q < 8; ++q) er[q] = enorm[j + q];
            uint2 gv[8];
#pragma unroll
            for (int q = 0; q < 8; ++q)
                gv[q] = ((const uint2*)(h1 + (size_t)er[q].x * 128))[sl];
#pragma unroll
            for (int q = 0; q < 8; ++q) {
                float nn = __int_as_float(er[q].y);
                float2 v0 = __half22float2(*(__half2*)&gv[q].x);
                float2 v1 = __half22float2(*(__half2*)&gv[q].y);
                acc.x += v0.x * nn; acc.y += v0.y * nn;
                acc.z += v1.x * nn; acc.w += v1.y * nn;
            }
        }
        for (; j < end; ++j) {
            int2 e0 = enorm[j];
            float nn = __int_as_float(e0.y);
            uint2 gv = ((const uint2*)(h1 + (size_t)e0.x * 128))[sl];
            float2 v0 = __half22float2(*(__half2*)&gv.x);
            float2 v1 = __half22float2(*(__half2*)&gv.y);
            acc.x += v0.x * nn; acc.y += v0.y * nn;
            acc.z += v1.x * nn; acc.w += v1.y * nn;
        }
        float p = fmaxf(acc.x + bb.x, 0.f) * ww.x + fmaxf(acc.y + bb.y, 0.f) * ww.y
                + fmaxf(acc.z + bb.z, 0.f) * ww.z + fmaxf(acc.w + bb.w, 0.f) * ww.w;
#pragma unroll
        for (int off = 16; off > 0; off >>= 1)   // stays within the 32-lane half
            p += __shfl_xor(p, off, 64);
        if (sl == 0 && i < n) s[i] = p;
    }
}

// ---------------- layer 2: per-thread CSR gather of s, unrolled x4 ----------------

__global__ void k_out2(const int* __restrict__ rowptr, const int2* __restrict__ enorm,
                       const float* __restrict__ dinv, const float* __restrict__ s,
                       const float* __restrict__ b2, float* __restrict__ out, int n) {
    int i = blockIdx.x * blockDim.x + threadIdx.x;
    if (i >= n) return;
    float di = dinv[i];
    float acc = di * di * s[i];            // self-loop
    int j = rowptr[i], end = rowptr[i + 1];
    float a0 = 0.f, a1 = 0.f, a2 = 0.f, a3 = 0.f;
    for (; j + 4 <= end; j += 4) {
        int2 e0 = enorm[j],     e1 = enorm[j + 1];
        int2 e2 = enorm[j + 2], e3 = enorm[j + 3];
        float s0 = s[e0.x], s1 = s[e1.x], s2 = s[e2.x], s3 = s[e3.x];
        a0 += __int_as_float(e0.y) * s0;
        a1 += __int_as_float(e1.y) * s1;
        a2 += __int_as_float(e2.y) * s2;
        a3 += __int_as_float(e3.y) * s3;
    }
    acc += (a0 + a1) + (a2 + a3);
    for (; j < end; ++j) {
        int2 e0 = enorm[j];
        acc += __int_as_float(e0.y) * s[e0.x];
    }
    out[i] = b2[0] + acc;
}

// ---------------- launch ----------------

extern "C" void kernel_launch(void* const* d_in, const int* in_sizes, int n_in,
                              void* d_out, int out_size, void* d_ws, size_t ws_size,
                              hipStream_t stream) {
    const float* x  = (const float*)d_in[0];
    const int*   ei = (const int*)d_in[1];   // [2,E] int32
    const float* W1 = (const float*)d_in[2];
    const float* b1 = (const float*)d_in[3];
    const float* W2 = (const float*)d_in[4];
    const float* b2 = (const float*)d_in[5];
    float* out = (float*)d_out;

    int n = in_sizes[0] / 128;
    int e = in_sizes[1] / 2;
    const int* srcp = ei;
    const int* dstp = ei + e;

    char* ws = (char*)d_ws;
    size_t off = 0;
    auto take = [&](size_t bytes) -> char* {
        char* p = ws + off;
        off += (bytes + 255) & ~(size_t)255;
        return p;
    };
    int*    deg    = (int*)take((size_t)n * 4);
    int*    rowptr = (int*)take((size_t)(n + 1) * 4);
    float*  dinv   = (float*)take((size_t)n * 4);
    float*  s      = (float*)take((size_t)n * 4);
    int*    pos    = (int*)take((size_t)e * 4);
    int2*   enorm  = (int2*)take((size_t)e * 8);
    int*    bsum   = (int*)take((size_t)512 * 4);
    __half* h1     = (__half*)take((size_t)n * 128 * 2);
    (void)ws_size;

    int egrid = (e + 255) / 256; if (egrid > 2048) egrid = 2048;
    int ngrid = (n + 255) / 256;
    int nscan = (n + 511) / 512;   // 98 blocks (must be <= 512)
    int gemmBlocks = (n + 63) / 64;

    hipMemsetAsync(deg, 0, (size_t)n * 4, stream);

    hipLaunchKernelGGL(k_gemm_count, dim3(gemmBlocks + 2048), dim3(256), 0, stream,
                       x, W1, h1, n, dstp, deg, pos, e, gemmBlocks);
    hipLaunchKernelGGL(k_scan1, dim3(nscan), dim3(512), 0, stream, deg, dinv, bsum, n);
    hipLaunchKernelGGL(k_scan3, dim3(nscan), dim3(512), 0, stream, deg, bsum, rowptr, n);
    hipLaunchKernelGGL(k_fill, dim3(egrid), dim3(256), 0, stream,
                       srcp, dstp, pos, rowptr, dinv, enorm, e);
    hipLaunchKernelGGL(k_agg_s, dim3(2048), dim3(256), 0, stream,
                       rowptr, enorm, dinv, h1, b1, W2, s, n);
    hipLaunchKernelGGL(k_out2, dim3(ngrid), dim3(256), 0, stream,
                       rowptr, enorm, dinv, s, b2, out, n);
}